// Round 6
// baseline (56.009 us; speedup 1.0000x reference)
//
#include <hip/hip_runtime.h>

// Fully-fused 4-layer MLP via f16 MFMA (fp32 accumulate), transposed problem
// G = H^T: activations live in registers across all layers (B operand).
// S=2: each wave owns 64 samples (two 32-col B groups) so every LDS A-fragment
// read feeds TWO MFMAs (halves the per-sample LDS-read cost, the R5 bottleneck).
// Weight strips 3-deep pipelined into LDS via global_load_lds with COUNTED
// vmcnt barriers. L4 stores straight from the C fragment.

typedef _Float16 half_t;
typedef _Float16 half8 __attribute__((ext_vector_type(8)));
typedef float f32x16 __attribute__((ext_vector_type(16)));
typedef unsigned int uint4v __attribute__((ext_vector_type(4)));
typedef int int2v __attribute__((ext_vector_type(2)));

#define M_TOTAL (64*2048)

// ---------------- prep kernel ----------------
// Strip-ordered fragment layout (halves), 512 halves per fragment-block:
//   L1: blocks 0..7     (strip 0: all 8 nt, ks=0, K padded 13->16)
//   L2: blocks 8..135   (strips 1..8:  nt*16 + ks)
//   L3: blocks 136..263 (strips 9..16)
//   L4: blocks 264..311 (strips 17..19, N padded 80->96)
// Within a block: wp[blk*512 + lane*8 + j] = W[ks*16 + (lane>>5)*8 + j][nt*32 + (lane&31)]
__global__ void prep_w(const float* __restrict__ W1, const float* __restrict__ W2,
                       const float* __restrict__ W3, const float* __restrict__ W4,
                       half_t* __restrict__ wp) {
    int tid = blockIdx.x * 256 + threadIdx.x;
    if (tid >= 312 * 512) return;
    int blk = tid >> 9, r = tid & 511;
    int lane = r >> 3, j = r & 7;
    const float* W; int K, N, nt, ks;
    if (blk < 8)        { W = W1; K = 13;  N = 256; nt = blk;              ks = 0; }
    else if (blk < 136) { W = W2; K = 256; N = 256; nt = (blk-8) >> 4;     ks = (blk-8) & 15; }
    else if (blk < 264) { W = W3; K = 256; N = 256; nt = (blk-136) >> 4;   ks = (blk-136) & 15; }
    else                { W = W4; K = 256; N = 80;  nt = (blk-264) >> 4;   ks = (blk-264) & 15; }
    int k = ks * 16 + (lane >> 5) * 8 + j;
    int n = nt * 32 + (lane & 31);
    float v = (k < K && n < N) ? W[k * N + n] : 0.f;
    wp[tid] = (half_t)v;
}

// ---------------- main kernel ----------------

__device__ __forceinline__ unsigned int pkrtz(float a, float b) {
    auto p = __builtin_amdgcn_cvt_pkrtz(a, b);
    return __builtin_bit_cast(unsigned int, p);
}

typedef const __attribute__((address_space(1))) unsigned int guint_t;
typedef __attribute__((address_space(3))) unsigned int luint_t;

// Stage `bytes` (multiple of 4096) from g into LDS l. 256 threads x 16 B.
__device__ __forceinline__ void stage_strip(const half_t* __restrict__ g,
                                            half_t* l, int bytes, int tid) {
    const char* gc = (const char*)g;
    char* lc = (char*)l;
    const int go = tid * 16;             // per-lane global offset
    const int lo = (tid >> 6) << 10;     // wave-uniform LDS offset (wave*1024)
#pragma unroll
    for (int r = 0; r < bytes; r += 4096) {
        __builtin_amdgcn_global_load_lds((guint_t*)(gc + r + go),
                                         (luint_t*)(lc + r + lo), 16, 0, 0);
    }
}

// strip index -> offset in wp (halves); folds at compile time after unroll
__device__ __forceinline__ int strip_off(int s) {
    if (s == 0)  return 0;
    if (s <= 8)  return (8   + (s - 1)  * 16) * 512;
    if (s <= 16) return (136 + (s - 9)  * 16) * 512;
    return (264 + (s - 17) * 16) * 512;
}

// Counted-vmcnt pipeline barrier: keep newest stage's loads in flight.
#define PIPE_BAR(Nstr) do {                                   \
    asm volatile("s_waitcnt vmcnt(" Nstr ")" ::: "memory");   \
    __builtin_amdgcn_sched_barrier(0);                        \
    __builtin_amdgcn_s_barrier();                             \
    __builtin_amdgcn_sched_barrier(0);                        \
} while (0)

// Repack one C fragment s-group into two B words (both lane-halves).
template <bool RELU>
__device__ __forceinline__ void repack(const f32x16& acc, int s,
                                       const float* biasnt, bool hi,
                                       unsigned int* Bw)   // -> Bw[0..3]
{
    float v[8];
#pragma unroll
    for (int q = 0; q < 8; ++q) {
        // C row = (reg&3) + 8*(reg>>2) + 4*(lane>=32), reg = 8s+q
        int f = (q & 3) + 8 * (q >> 2) + (hi ? 4 : 0);
        float t = acc[8 * s + q] + biasnt[16 * s + f];
        v[q] = RELU ? fmaxf(t, 0.f) : t;
    }
    unsigned int P0 = pkrtz(v[0], v[1]);   // lo:(0,1)  hi:(4,5)
    unsigned int P1 = pkrtz(v[2], v[3]);   // lo:(2,3)  hi:(6,7)
    unsigned int P2 = pkrtz(v[4], v[5]);   // lo:(8,9)  hi:(12,13)
    unsigned int P3 = pkrtz(v[6], v[7]);   // lo:(10,11) hi:(14,15)
    // One swap fills two B-words: word0=[P0.lo|P2.lo], word2=[P0.hi|P2.hi]
    int2v r02 = __builtin_amdgcn_permlane32_swap((int)P0, (int)P2, false, false);
    int2v r13 = __builtin_amdgcn_permlane32_swap((int)P1, (int)P3, false, false);
    Bw[0] = (unsigned int)r02.x;
    Bw[1] = (unsigned int)r13.x;
    Bw[2] = (unsigned int)r02.y;
    Bw[3] = (unsigned int)r13.y;
}

// One 32-feature output tile for BOTH sample groups: K = NKS*16 from LDS strip.
// Each A read feeds two MFMAs (independent acc chains).
template <int NKS, bool RELU>
__device__ __forceinline__ void dense_tile2(const half_t* astrip,
                                            const unsigned int (&Bin)[2][16][4],
                                            unsigned int (*Bout0)[4],
                                            unsigned int (*Bout1)[4],
                                            const float* biasnt, int lane, bool hi)
{
    f32x16 acc0 = {}, acc1 = {};
#pragma unroll
    for (int ks = 0; ks < NKS; ++ks) {
        half8 a = *(const half8*)(astrip + ((ks * 64 + lane) << 3));
        uint4v b0 = { Bin[0][ks][0], Bin[0][ks][1], Bin[0][ks][2], Bin[0][ks][3] };
        uint4v b1 = { Bin[1][ks][0], Bin[1][ks][1], Bin[1][ks][2], Bin[1][ks][3] };
        acc0 = __builtin_amdgcn_mfma_f32_32x32x16_f16(a, __builtin_bit_cast(half8, b0),
                                                      acc0, 0, 0, 0);
        acc1 = __builtin_amdgcn_mfma_f32_32x32x16_f16(a, __builtin_bit_cast(half8, b1),
                                                      acc1, 0, 0, 0);
    }
#pragma unroll
    for (int s = 0; s < 2; ++s) {
        repack<RELU>(acc0, s, biasnt, hi, Bout0[s]);
        repack<RELU>(acc1, s, biasnt, hi, Bout1[s]);
    }
}

// L4 tile for both groups: 32 features, direct global stores from C fragments.
__device__ __forceinline__ void out_tile2(const half_t* astrip,
                                          const unsigned int (&Bin)[2][16][4],
                                          const float* biasnt, float* __restrict__ out,
                                          int m0, int nt, int lane, bool hi)
{
    f32x16 acc0 = {}, acc1 = {};
#pragma unroll
    for (int ks = 0; ks < 16; ++ks) {
        half8 a = *(const half8*)(astrip + ((ks * 64 + lane) << 3));
        uint4v b0 = { Bin[0][ks][0], Bin[0][ks][1], Bin[0][ks][2], Bin[0][ks][3] };
        uint4v b1 = { Bin[1][ks][0], Bin[1][ks][1], Bin[1][ks][2], Bin[1][ks][3] };
        acc0 = __builtin_amdgcn_mfma_f32_32x32x16_f16(a, __builtin_bit_cast(half8, b0),
                                                      acc0, 0, 0, 0);
        acc1 = __builtin_amdgcn_mfma_f32_32x32x16_f16(a, __builtin_bit_cast(half8, b1),
                                                      acc1, 0, 0, 0);
    }
#pragma unroll
    for (int g = 0; g < 2; ++g) {
        const f32x16& acc = g ? acc1 : acc0;
        float* orow = out + (long)(m0 + g * 32 + (lane & 31)) * 80 + nt * 32;
#pragma unroll
        for (int reg = 0; reg < 16; ++reg) {
            if (nt == 2 && (reg >> 2) >= 2) continue;   // f = 64+rr < 80 <=> rr < 16
            int rr = (reg & 3) + 8 * (reg >> 2) + (hi ? 4 : 0);
            orow[rr] = acc[reg] + biasnt[rr];
        }
    }
}

__global__ __launch_bounds__(256, 2) void mlp_mfma(
    const float* __restrict__ x, const half_t* __restrict__ wp,
    const float* __restrict__ b1, const float* __restrict__ b2,
    const float* __restrict__ b3, const float* __restrict__ b4,
    float* __restrict__ out)
{
    __shared__ half_t wbuf[3][8192];     // 3-deep strip pipeline (3 x 16 KB)
    __shared__ float  bias_lds[864];     // b1|b2|b3 (256 each) | b4 (96, padded)

    const int tid  = threadIdx.x;
    const int lane = tid & 63;
    const bool hi  = lane >= 32;
    const int m0   = (blockIdx.x * 4 + (tid >> 6)) * 64;   // 64 samples per wave

    bias_lds[tid] = b1[tid];
    bias_lds[256 + tid] = b2[tid];
    bias_lds[512 + tid] = b3[tid];
    if (tid < 96) bias_lds[768 + tid] = (tid < 80) ? b4[tid] : 0.f;

    stage_strip(wp + strip_off(0), wbuf[0], 8192, tid);    // L1 strip (8 KB)
    stage_strip(wp + strip_off(1), wbuf[1], 16384, tid);

    unsigned int BA[2][16][4], BB[2][16][4];

    // Layer-1 B fragments from fp32 x: lane holds x[m][k], k = (hi?8:0)+j
#pragma unroll
    for (int g = 0; g < 2; ++g) {
        const float* xp = x + (long)(m0 + g * 32 + (lane & 31)) * 13;
        float xv[8];
        if (!hi) {
#pragma unroll
            for (int j = 0; j < 8; ++j) xv[j] = xp[j];
        } else {
#pragma unroll
            for (int j = 0; j < 5; ++j) xv[j] = xp[8 + j];
            xv[5] = xv[6] = xv[7] = 0.f;
        }
        BA[g][0][0] = pkrtz(xv[0], xv[1]);
        BA[g][0][1] = pkrtz(xv[2], xv[3]);
        BA[g][0][2] = pkrtz(xv[4], xv[5]);
        BA[g][0][3] = pkrtz(xv[6], xv[7]);
    }

    __syncthreads();   // phase-0 entry: bias + strips 0,1 resident

    // ---- Phase 0 / L1: strip 0 (8 nt-blocks), 13->256 ----
    stage_strip(wp + strip_off(2), wbuf[2], 16384, tid);
#pragma unroll
    for (int nt = 0; nt < 8; ++nt)
        dense_tile2<1, true>(&wbuf[0][nt * 512], BA, &BB[0][2 * nt], &BB[1][2 * nt],
                             bias_lds + nt * 32, lane, hi);

    // ---- Phases 1..8 / L2: strips 1..8, 256->256 ----
#pragma unroll
    for (int i = 0; i < 8; ++i) {
        const int k = 1 + i;
        PIPE_BAR("4");                              // strip k landed; k+1 in flight
        stage_strip(wp + strip_off(k + 2), wbuf[(k + 2) % 3], 16384, tid);
        dense_tile2<16, true>(&wbuf[k % 3][0], BB, &BA[0][2 * i], &BA[1][2 * i],
                              bias_lds + 256 + i * 32, lane, hi);
    }

    // ---- Phases 9..16 / L3: strips 9..16, 256->256 ----
#pragma unroll
    for (int i = 0; i < 8; ++i) {
        const int k = 9 + i;
        PIPE_BAR("4");
        stage_strip(wp + strip_off(k + 2), wbuf[(k + 2) % 3], 16384, tid);
        dense_tile2<16, true>(&wbuf[k % 3][0], BA, &BB[0][2 * i], &BB[1][2 * i],
                              bias_lds + 512 + i * 32, lane, hi);
    }

    // ---- Phases 17..19 / L4: strips 17..19, 256->80, direct stores ----
#pragma unroll
    for (int i = 0; i < 3; ++i) {
        const int k = 17 + i;
        if (i < 2) PIPE_BAR("4");                   // over-waits stores; safe
        else       PIPE_BAR("0");                   // last strip must be fully landed
        if (i == 0) stage_strip(wp + strip_off(19), wbuf[19 % 3], 16384, tid);
        out_tile2(&wbuf[k % 3][0], BB, bias_lds + 768 + i * 32, out, m0, i, lane, hi);
    }
}

// ---------------- launch ----------------

extern "C" void kernel_launch(void* const* d_in, const int* in_sizes, int n_in,
                              void* d_out, int out_size, void* d_ws, size_t ws_size,
                              hipStream_t stream) {
    const float* x  = (const float*)d_in[0];
    const float* W1 = (const float*)d_in[1];
    const float* b1 = (const float*)d_in[2];
    const float* W2 = (const float*)d_in[3];
    const float* b2 = (const float*)d_in[4];
    const float* W3 = (const float*)d_in[5];
    const float* b3 = (const float*)d_in[6];
    const float* W4 = (const float*)d_in[7];
    const float* b4 = (const float*)d_in[8];
    float* out = (float*)d_out;

    half_t* wp = (half_t*)d_ws;

    hipLaunchKernelGGL(prep_w, dim3(624), dim3(256), 0, stream, W1, W2, W3, W4, wp);
    hipLaunchKernelGGL(mlp_mfma, dim3(M_TOTAL / 256), dim3(256), 0, stream,
                       x, wp, b1, b2, b3, b4, out);
}